// Round 2
// baseline (630.149 us; speedup 1.0000x reference)
//
#include <hip/hip_runtime.h>
#include <stdint.h>

#define BATCH 256
#define NV 10475
#define NJ 55
#define NB 10
#define PB 486          // (NJ-1)*9
#define VC (NV*3)       // 31425
#define JCH 8
#define JCHUNK 1312     // 8*1312 >= NV

__constant__ int c_parents[NJ] = {
  -1,0,0,0,1,2,3,4,5,6,7,8,9,9,9,12,13,14,16,17,18,19,15,15,15,
  20,25,26,20,28,29,20,31,32,20,34,35,20,37,38,21,40,41,21,43,44,
  21,46,47,21,49,50,21,52,53};

// ---------------- v_shaped = v_template + shapedirs@beta + exprdirs@expr ----
// writes v_shaped (fp32) into the verts region of d_out (reused as scratch)
__global__ __launch_bounds__(256) void k_vshaped(
    const float* __restrict__ vt, const float* __restrict__ sd,
    const float* __restrict__ ed, const float* __restrict__ bs,
    const float* __restrict__ es, float* __restrict__ vsh) {
  int b = blockIdx.y;
  int n = blockIdx.x*256 + threadIdx.x;
  if (n >= NV) return;
  float s[NB], e[NB];
  #pragma unroll
  for (int k=0;k<NB;k++){ s[k]=bs[b*NB+k]; e[k]=es[b*NB+k]; }
  const float* sp = sd + n*30;   // (NV, 3, 10)
  const float* ep = ed + n*30;
  float* o = vsh + (b*NV+n)*3;
  #pragma unroll
  for (int c=0;c<3;c++){
    float a = vt[n*3+c];
    #pragma unroll
    for (int k=0;k<NB;k++) a += s[k]*sp[c*10+k];
    #pragma unroll
    for (int k=0;k<NB;k++) a += e[k]*ep[c*10+k];
    o[c] = a;
  }
}

// ---------------- joints = J_regressor @ v_shaped (two-stage, deterministic)
__global__ __launch_bounds__(256) void k_joints_partial(
    const float* __restrict__ jreg, const float* __restrict__ vsh,
    float* __restrict__ part) {
  int b = blockIdx.y, ch = blockIdx.x;
  int jj = threadIdx.x >> 2, g = threadIdx.x & 3;
  float a0=0.f,a1=0.f,a2=0.f;
  int nend = min((ch+1)*JCHUNK, NV);
  if (jj < NJ) {
    const float* jr = jreg + jj*NV;
    for (int n = ch*JCHUNK + g; n < nend; n += 4) {
      float w = jr[n];
      const float* v = vsh + (b*NV+n)*3;
      a0 += w*v[0]; a1 += w*v[1]; a2 += w*v[2];
    }
  }
  a0 += __shfl_xor(a0,1); a0 += __shfl_xor(a0,2);
  a1 += __shfl_xor(a1,1); a1 += __shfl_xor(a1,2);
  a2 += __shfl_xor(a2,1); a2 += __shfl_xor(a2,2);
  if (jj < NJ && g == 0) {
    float* p = part + ((b*JCH+ch)*NJ + jj)*3;
    p[0]=a0; p[1]=a1; p[2]=a2;
  }
}

__global__ __launch_bounds__(256) void k_joints_reduce(
    const float* __restrict__ part, float* __restrict__ joints) {
  int b = blockIdx.x, t = threadIdx.x;
  if (t >= NJ*3) return;
  float a = 0.f;
  #pragma unroll
  for (int ch=0; ch<JCH; ch++) a += part[(b*JCH+ch)*NJ*3 + t];
  joints[b*NJ*3 + t] = a;
}

// ---------------- full_pose gather helper ----------------------------------
__device__ __forceinline__ const float* pose_src(int j, int b,
    const float* wrot, const float* bpose, const float* jaw, const float* leye,
    const float* reye, const float* lhand, const float* rhand) {
  if (j==0)  return wrot  + b*9;
  if (j<=21) return bpose + (b*21 + (j-1))*9;
  if (j==22) return jaw   + b*9;
  if (j==23) return leye  + b*9;
  if (j==24) return reye  + b*9;
  if (j<=39) return lhand + (b*15 + (j-25))*9;
  return rhand + (b*15 + (j-40))*9;
}

// ---------------- pose_feature = (full_pose[:,1:] - I).reshape(B,486) -------
__global__ __launch_bounds__(512) void k_posefeat(
    const float* __restrict__ bpose, const float* __restrict__ jaw,
    const float* __restrict__ leye, const float* __restrict__ reye,
    const float* __restrict__ lhand, const float* __restrict__ rhand,
    float* __restrict__ pf) {
  int b = blockIdx.x, t = threadIdx.x;
  if (t >= PB) return;
  int jj = t/9, rc = t - jj*9;
  const float* rs = pose_src(jj+1, b, nullptr, bpose, jaw, leye, reye, lhand, rhand);
  float v = rs[rc];
  if (rc==0 || rc==4 || rc==8) v -= 1.0f;
  pf[b*PB + t] = v;
}

// ---------------- kinematic chain + A_rel + joints_out ----------------------
__global__ __launch_bounds__(64) void k_chain(
    const float* __restrict__ wrot, const float* __restrict__ bpose,
    const float* __restrict__ jaw, const float* __restrict__ leye,
    const float* __restrict__ reye, const float* __restrict__ lhand,
    const float* __restrict__ rhand, const float* __restrict__ wtsl,
    const float* __restrict__ joints, float* __restrict__ chain,
    float* __restrict__ arel, float* __restrict__ jout) {
  int b = blockIdx.x*64 + threadIdx.x;   // grid 4 x 64 = 256 batches
  const float* jb = joints + b*NJ*3;
  for (int j=0;j<NJ;j++){
    const float* R = pose_src(j, b, wrot, bpose, jaw, leye, reye, lhand, rhand);
    int p = c_parents[j];
    float t0,t1,t2;
    if (p < 0){ t0=jb[0]; t1=jb[1]; t2=jb[2]; }
    else { t0=jb[j*3+0]-jb[p*3+0]; t1=jb[j*3+1]-jb[p*3+1]; t2=jb[j*3+2]-jb[p*3+2]; }
    float* Cj = chain + (b*NJ+j)*12;
    if (p < 0){
      #pragma unroll
      for (int r=0;r<3;r++){
        Cj[r*4+0]=R[r*3+0]; Cj[r*4+1]=R[r*3+1]; Cj[r*4+2]=R[r*3+2];
      }
      Cj[3]=t0; Cj[7]=t1; Cj[11]=t2;
    } else {
      const float* Cp = chain + (b*NJ+p)*12;
      float P[12];
      #pragma unroll
      for (int i=0;i<12;i++) P[i]=Cp[i];
      #pragma unroll
      for (int r=0;r<3;r++){
        float p0=P[r*4+0], p1=P[r*4+1], p2=P[r*4+2], p3=P[r*4+3];
        Cj[r*4+0] = p0*R[0]+p1*R[3]+p2*R[6];
        Cj[r*4+1] = p0*R[1]+p1*R[4]+p2*R[7];
        Cj[r*4+2] = p0*R[2]+p1*R[5]+p2*R[8];
        Cj[r*4+3] = p0*t0 + p1*t1 + p2*t2 + p3;
      }
    }
  }
  float wx=wtsl[b*3+0], wy=wtsl[b*3+1], wz=wtsl[b*3+2];
  for (int j=0;j<NJ;j++){
    const float* C = chain + (b*NJ+j)*12;
    float P[12];
    #pragma unroll
    for (int i=0;i<12;i++) P[i]=C[i];
    float j0=jb[j*3+0], j1=jb[j*3+1], j2=jb[j*3+2];
    float* A = arel + (b*NJ+j)*12;
    #pragma unroll
    for (int r=0;r<3;r++){
      A[r*4+0]=P[r*4+0]; A[r*4+1]=P[r*4+1]; A[r*4+2]=P[r*4+2];
      A[r*4+3]=P[r*4+3] - (P[r*4+0]*j0 + P[r*4+1]*j1 + P[r*4+2]*j2);
    }
    jout[(b*NJ+j)*3+0]=P[3] +wx;
    jout[(b*NJ+j)*3+1]=P[7] +wy;
    jout[(b*NJ+j)*3+2]=P[11]+wz;
  }
}

// ---------------- v_posed += pose_feature @ posedirs (in-place on vsh) ------
// grid (ceil(VC/512), 16), block 256. 16 batches/block, 2 cols/thread.
__global__ __launch_bounds__(256) void k_vposed(
    const float* __restrict__ pd, const float* __restrict__ pf,
    float* __restrict__ vsh) {
  __shared__ __align__(16) float spf[PB*16];
  int bb = blockIdx.y*16;
  for (int idx=threadIdx.x; idx<PB*16; idx+=256){
    int i = idx/PB, k = idx - i*PB;          // coalesced read along k
    spf[k*16 + i] = pf[(bb+i)*PB + k];
  }
  __syncthreads();
  int col0 = blockIdx.x*512 + threadIdx.x;
  int col1 = col0 + 256;
  bool v0 = col0 < VC, v1 = col1 < VC;
  float acc0[16], acc1[16];
  #pragma unroll
  for (int i=0;i<16;i++){ acc0[i]=0.f; acc1[i]=0.f; }
  for (int k=0;k<PB;k++){
    float w0 = v0 ? pd[k*(size_t)VC+col0] : 0.f;
    float w1 = v1 ? pd[k*(size_t)VC+col1] : 0.f;
    const float4* s4 = (const float4*)(spf + k*16);
    float4 x=s4[0], y=s4[1], z=s4[2], w=s4[3];
    float sv[16] = {x.x,x.y,x.z,x.w, y.x,y.y,y.z,y.w,
                    z.x,z.y,z.z,z.w, w.x,w.y,w.z,w.w};
    #pragma unroll
    for (int i=0;i<16;i++){ acc0[i] += sv[i]*w0; acc1[i] += sv[i]*w1; }
  }
  if (v0){
    #pragma unroll
    for (int i=0;i<16;i++) vsh[(size_t)(bb+i)*VC + col0] += acc0[i];
  }
  if (v1){
    #pragma unroll
    for (int i=0;i<16;i++) vsh[(size_t)(bb+i)*VC + col1] += acc1[i];
  }
}

// ---------------- skinning: T = sum_j w[n,j] A_rel[b,j]; verts --------------
// reads v_posed from the verts region of d_out and overwrites it in place
// (1:1 thread->vertex map: read happens before the write in the same thread)
__global__ __launch_bounds__(256) void k_verts(
    const float* __restrict__ lw, const float* __restrict__ arel,
    const float* __restrict__ wtsl, float* __restrict__ out) {
  __shared__ __align__(16) float sA[NJ*12];
  int b = blockIdx.y;
  for (int idx=threadIdx.x; idx<NJ*12; idx+=256) sA[idx] = arel[b*NJ*12 + idx];
  __syncthreads();
  int n = blockIdx.x*256 + threadIdx.x;
  if (n >= NV) return;
  float T[12];
  #pragma unroll
  for (int e=0;e<12;e++) T[e]=0.f;
  const float* wp = lw + n*NJ;
  for (int j=0;j<NJ;j++){
    float w = wp[j];
    const float4* A4 = (const float4*)(sA + j*12);   // 48B stride, 16B aligned
    float4 a=A4[0], c=A4[1], d=A4[2];
    T[0]+=w*a.x; T[1]+=w*a.y; T[2] +=w*a.z; T[3] +=w*a.w;
    T[4]+=w*c.x; T[5]+=w*c.y; T[6] +=w*c.z; T[7] +=w*c.w;
    T[8]+=w*d.x; T[9]+=w*d.y; T[10]+=w*d.z; T[11]+=w*d.w;
  }
  float* op = out + (size_t)(b*NV+n)*3;
  float x=op[0], y=op[1], z=op[2];
  float tx=wtsl[b*3+0], ty=wtsl[b*3+1], tz=wtsl[b*3+2];
  op[0] = T[0]*x + T[1]*y + T[2] *z + T[3]  + tx;
  op[1] = T[4]*x + T[5]*y + T[6] *z + T[7]  + ty;
  op[2] = T[8]*x + T[9]*y + T[10]*z + T[11] + tz;
}

extern "C" void kernel_launch(void* const* d_in, const int* in_sizes, int n_in,
                              void* d_out, int out_size, void* d_ws, size_t ws_size,
                              hipStream_t stream) {
  const float* wrot   = (const float*)d_in[0];
  const float* wtsl   = (const float*)d_in[1];
  const float* bshape = (const float*)d_in[2];
  const float* bpose  = (const float*)d_in[3];
  const float* lhand  = (const float*)d_in[4];
  const float* rhand  = (const float*)d_in[5];
  const float* eshape = (const float*)d_in[6];
  const float* jaw    = (const float*)d_in[7];
  const float* leye   = (const float*)d_in[8];
  const float* reye   = (const float*)d_in[9];
  const float* vt     = (const float*)d_in[10];
  const float* sd     = (const float*)d_in[11];
  const float* ed     = (const float*)d_in[12];
  const float* pd     = (const float*)d_in[13];
  const float* jreg   = (const float*)d_in[14];
  const float* lw     = (const float*)d_in[15];
  float* out = (float*)d_out;

  // d_out verts region doubles as v_shaped / v_posed scratch (fp32, 1:1 layout)
  float* vsh  = out;                               // BATCH*VC floats
  float* jout = out + (size_t)BATCH*NV*3;          // BATCH*NJ*3 floats

  float* ws     = (float*)d_ws;                    // only ~3.4 MB of scratch
  float* joints = ws;                              // BATCH*NJ*3
  float* pf     = joints + (size_t)BATCH*NJ*3;     // BATCH*PB
  float* chain  = pf     + (size_t)BATCH*PB;       // BATCH*NJ*12
  float* arel   = chain  + (size_t)BATCH*NJ*12;    // BATCH*NJ*12
  float* part   = arel   + (size_t)BATCH*NJ*12;    // BATCH*JCH*NJ*3

  k_vshaped       <<<dim3(41, BATCH), 256, 0, stream>>>(vt, sd, ed, bshape, eshape, vsh);
  k_posefeat      <<<dim3(BATCH),     512, 0, stream>>>(bpose, jaw, leye, reye, lhand, rhand, pf);
  k_joints_partial<<<dim3(JCH, BATCH),256, 0, stream>>>(jreg, vsh, part);
  k_joints_reduce <<<dim3(BATCH),     256, 0, stream>>>(part, joints);
  k_chain         <<<dim3(4),          64, 0, stream>>>(wrot, bpose, jaw, leye, reye, lhand,
                                                        rhand, wtsl, joints, chain, arel, jout);
  k_vposed        <<<dim3(62, 16),    256, 0, stream>>>(pd, pf, vsh);
  k_verts         <<<dim3(41, BATCH), 256, 0, stream>>>(lw, arel, wtsl, out);
}

// Round 3
// 574.728 us; speedup vs baseline: 1.0964x; 1.0964x over previous
//
#include <hip/hip_runtime.h>
#include <stdint.h>

#define BATCH 256
#define NV 10475
#define NJ 55
#define NB 10
#define PB 486          // (NJ-1)*9
#define VC (NV*3)       // 31425
#define JCH 8
#define JCHUNK 1312     // 8*1312 >= NV
#define KP 512          // PB padded to 16 chunks of 32
#define BKC 32
#define NCHUNK 16
#define BN 64

typedef short bf16x8 __attribute__((ext_vector_type(8)));
typedef float f32x4  __attribute__((ext_vector_type(4)));

__constant__ int c_parents[NJ] = {
  -1,0,0,0,1,2,3,4,5,6,7,8,9,9,9,12,13,14,16,17,18,19,15,15,15,
  20,25,26,20,28,29,20,31,32,20,34,35,20,37,38,21,40,41,21,43,44,
  21,46,47,21,49,50,21,52,53};

__device__ __forceinline__ unsigned short f2bf(float x){   // RNE fp32->bf16
  uint32_t u = __float_as_uint(x);
  uint32_t r = (u + 0x7fffu + ((u >> 16) & 1u)) >> 16;
  return (unsigned short)r;
}

// ---------------- v_shaped = v_template + shapedirs@beta + exprdirs@expr ----
// writes v_shaped (fp32) into the verts region of d_out (reused as scratch)
__global__ __launch_bounds__(256) void k_vshaped(
    const float* __restrict__ vt, const float* __restrict__ sd,
    const float* __restrict__ ed, const float* __restrict__ bs,
    const float* __restrict__ es, float* __restrict__ vsh) {
  int b = blockIdx.y;
  int n = blockIdx.x*256 + threadIdx.x;
  if (n >= NV) return;
  float s[NB], e[NB];
  #pragma unroll
  for (int k=0;k<NB;k++){ s[k]=bs[b*NB+k]; e[k]=es[b*NB+k]; }
  const float* sp = sd + n*30;   // (NV, 3, 10)
  const float* ep = ed + n*30;
  float* o = vsh + ((size_t)b*NV+n)*3;
  #pragma unroll
  for (int c=0;c<3;c++){
    float a = vt[n*3+c];
    #pragma unroll
    for (int k=0;k<NB;k++) a += s[k]*sp[c*10+k];
    #pragma unroll
    for (int k=0;k<NB;k++) a += e[k]*ep[c*10+k];
    o[c] = a;
  }
}

// ---------------- joints = J_regressor @ v_shaped (two-stage, deterministic)
// wave-per-joint: lanes walk n contiguously -> coalesced jreg and vsh reads
__global__ __launch_bounds__(256) void k_joints_partial(
    const float* __restrict__ jreg, const float* __restrict__ vsh,
    float* __restrict__ part) {
  int b = blockIdx.y, ch = blockIdx.x;
  int w = threadIdx.x >> 6, l = threadIdx.x & 63;
  int n0 = ch*JCHUNK, nend = min(n0 + JCHUNK, NV);
  for (int jj = w; jj < NJ; jj += 4){
    const float* jr = jreg + (size_t)jj*NV;
    float a0=0.f, a1=0.f, a2=0.f;
    for (int n = n0 + l; n < nend; n += 64){
      float wt = jr[n];
      const float* v = vsh + ((size_t)b*NV + n)*3;
      a0 += wt*v[0]; a1 += wt*v[1]; a2 += wt*v[2];
    }
    #pragma unroll
    for (int s=32; s>=1; s>>=1){
      a0 += __shfl_xor(a0,s); a1 += __shfl_xor(a1,s); a2 += __shfl_xor(a2,s);
    }
    if (l == 0){
      float* p = part + ((size_t)(b*JCH+ch)*NJ + jj)*3;
      p[0]=a0; p[1]=a1; p[2]=a2;
    }
  }
}

__global__ __launch_bounds__(256) void k_joints_reduce(
    const float* __restrict__ part, float* __restrict__ joints) {
  int b = blockIdx.x, t = threadIdx.x;
  if (t >= NJ*3) return;
  float a = 0.f;
  #pragma unroll
  for (int ch=0; ch<JCH; ch++) a += part[((size_t)(b*JCH+ch)*NJ)*3 + t];
  joints[(size_t)b*NJ*3 + t] = a;
}

// ---------------- full_pose gather helper ----------------------------------
__device__ __forceinline__ const float* pose_src(int j, int b,
    const float* wrot, const float* bpose, const float* jaw, const float* leye,
    const float* reye, const float* lhand, const float* rhand) {
  if (j==0)  return wrot  + b*9;
  if (j<=21) return bpose + (b*21 + (j-1))*9;
  if (j==22) return jaw   + b*9;
  if (j==23) return leye  + b*9;
  if (j==24) return reye  + b*9;
  if (j<=39) return lhand + (b*15 + (j-25))*9;
  return rhand + (b*15 + (j-40))*9;
}

// ---------------- pose_feature -> bf16 [256][512] (MFMA A-operand layout) ---
__global__ __launch_bounds__(512) void k_posefeat(
    const float* __restrict__ bpose, const float* __restrict__ jaw,
    const float* __restrict__ leye, const float* __restrict__ reye,
    const float* __restrict__ lhand, const float* __restrict__ rhand,
    unsigned short* __restrict__ pfb) {
  int b = blockIdx.x, t = threadIdx.x;     // t < 512
  unsigned short o = 0;
  if (t < PB){
    int jj = t/9, rc = t - jj*9;
    const float* rs = pose_src(jj+1, b, nullptr, bpose, jaw, leye, reye, lhand, rhand);
    float v = rs[rc];
    if (rc==0 || rc==4 || rc==8) v -= 1.0f;
    o = f2bf(v);
  }
  pfb[(size_t)b*KP + t] = o;
}

// ---------------- kinematic chain + A_rel + joints_out ----------------------
__global__ __launch_bounds__(64) void k_chain(
    const float* __restrict__ wrot, const float* __restrict__ bpose,
    const float* __restrict__ jaw, const float* __restrict__ leye,
    const float* __restrict__ reye, const float* __restrict__ lhand,
    const float* __restrict__ rhand, const float* __restrict__ wtsl,
    const float* __restrict__ joints, float* __restrict__ chain,
    float* __restrict__ arel, float* __restrict__ jout) {
  int b = blockIdx.x*64 + threadIdx.x;   // grid 4 x 64 = 256 batches
  const float* jb = joints + (size_t)b*NJ*3;
  for (int j=0;j<NJ;j++){
    const float* R = pose_src(j, b, wrot, bpose, jaw, leye, reye, lhand, rhand);
    int p = c_parents[j];
    float t0,t1,t2;
    if (p < 0){ t0=jb[0]; t1=jb[1]; t2=jb[2]; }
    else { t0=jb[j*3+0]-jb[p*3+0]; t1=jb[j*3+1]-jb[p*3+1]; t2=jb[j*3+2]-jb[p*3+2]; }
    float* Cj = chain + ((size_t)b*NJ+j)*12;
    if (p < 0){
      #pragma unroll
      for (int r=0;r<3;r++){
        Cj[r*4+0]=R[r*3+0]; Cj[r*4+1]=R[r*3+1]; Cj[r*4+2]=R[r*3+2];
      }
      Cj[3]=t0; Cj[7]=t1; Cj[11]=t2;
    } else {
      const float* Cp = chain + ((size_t)b*NJ+p)*12;
      float P[12];
      #pragma unroll
      for (int i=0;i<12;i++) P[i]=Cp[i];
      #pragma unroll
      for (int r=0;r<3;r++){
        float p0=P[r*4+0], p1=P[r*4+1], p2=P[r*4+2], p3=P[r*4+3];
        Cj[r*4+0] = p0*R[0]+p1*R[3]+p2*R[6];
        Cj[r*4+1] = p0*R[1]+p1*R[4]+p2*R[7];
        Cj[r*4+2] = p0*R[2]+p1*R[5]+p2*R[8];
        Cj[r*4+3] = p0*t0 + p1*t1 + p2*t2 + p3;
      }
    }
  }
  float wx=wtsl[b*3+0], wy=wtsl[b*3+1], wz=wtsl[b*3+2];
  for (int j=0;j<NJ;j++){
    const float* C = chain + ((size_t)b*NJ+j)*12;
    float P[12];
    #pragma unroll
    for (int i=0;i<12;i++) P[i]=C[i];
    float j0=jb[j*3+0], j1=jb[j*3+1], j2=jb[j*3+2];
    float* A = arel + ((size_t)b*NJ+j)*12;
    #pragma unroll
    for (int r=0;r<3;r++){
      A[r*4+0]=P[r*4+0]; A[r*4+1]=P[r*4+1]; A[r*4+2]=P[r*4+2];
      A[r*4+3]=P[r*4+3] - (P[r*4+0]*j0 + P[r*4+1]*j1 + P[r*4+2]*j2);
    }
    jout[((size_t)b*NJ+j)*3+0]=P[3] +wx;
    jout[((size_t)b*NJ+j)*3+1]=P[7] +wy;
    jout[((size_t)b*NJ+j)*3+2]=P[11]+wz;
  }
}

// ---------------- v_posed += pose_feature @ posedirs (bf16 MFMA) ------------
// One block = 4 waves covers ALL 256 batches x 64 cols -> posedirs read once.
// A-fragments straight from global pfb (L2-resident). B-tile dbuf in LDS.
__global__ __launch_bounds__(256) void k_vposed(
    const float* __restrict__ pd, const unsigned short* __restrict__ pfb,
    float* __restrict__ vsh) {
  __shared__ __align__(16) unsigned short sB[2][BN*40];  // B[n][k], stride 40
  const int tid  = threadIdx.x;
  const int w    = tid >> 6, lane = tid & 63;
  const int m16  = lane & 15, quad = lane >> 4;
  const int col0 = blockIdx.x * BN;

  f32x4 acc[4][4];
  #pragma unroll
  for (int i=0;i<4;i++)
    #pragma unroll
    for (int j=0;j<4;j++) acc[i][j] = (f32x4){0.f,0.f,0.f,0.f};

  // stage chunk 0
  #pragma unroll
  for (int i=0;i<8;i++){
    int idx = tid + i*256;
    int k = idx >> 6, n = idx & 63;
    int cc = col0 + n;
    float v = (k < PB && cc < VC) ? pd[(size_t)k*VC + cc] : 0.f;
    sB[0][n*40 + k] = f2bf(v);
  }

  for (int c=0; c<NCHUNK; c++){
    __syncthreads();
    const unsigned short* sBc = sB[c&1];
    const int k0 = c*BKC;
    bf16x8 a[4], bb[4];
    #pragma unroll
    for (int mi=0;mi<4;mi++){
      int row = w*64 + mi*16 + m16;
      a[mi] = *((const bf16x8*)(pfb + (size_t)row*KP + k0 + quad*8));
    }
    #pragma unroll
    for (int ni=0;ni<4;ni++)
      bb[ni] = *((const bf16x8*)(sBc + (ni*16 + m16)*40 + quad*8));
    #pragma unroll
    for (int mi=0;mi<4;mi++)
      #pragma unroll
      for (int ni=0;ni<4;ni++)
        acc[mi][ni] = __builtin_amdgcn_mfma_f32_16x16x32_bf16(
                          a[mi], bb[ni], acc[mi][ni], 0, 0, 0);
    if (c+1 < NCHUNK){
      unsigned short* sBn = sB[(c+1)&1];
      const int k0n = (c+1)*BKC;
      #pragma unroll
      for (int i=0;i<8;i++){
        int idx = tid + i*256;
        int k = idx >> 6, n = idx & 63;
        int kk = k0n + k, cc = col0 + n;
        float v = (kk < PB && cc < VC) ? pd[(size_t)kk*VC + cc] : 0.f;
        sBn[n*40 + k] = f2bf(v);
      }
    }
  }
  // epilogue: D[row=quad*4+r (within tile), col=m16]
  #pragma unroll
  for (int mi=0;mi<4;mi++){
    int rbase = w*64 + mi*16 + quad*4;
    #pragma unroll
    for (int ni=0;ni<4;ni++){
      int col = col0 + ni*16 + m16;
      if (col < VC){
        #pragma unroll
        for (int r=0;r<4;r++)
          vsh[(size_t)(rbase + r)*VC + col] += acc[mi][ni][r];
      }
    }
  }
}

// ---------------- skinning: T = sum_j w[n,j] A_rel[b,j]; verts --------------
// lw slab staged to LDS via coalesced loads; per-thread LDS reads stride 55
// (coprime with 32 banks -> conflict-free). In-place on d_out verts.
__global__ __launch_bounds__(256) void k_verts(
    const float* __restrict__ lw, const float* __restrict__ arel,
    const float* __restrict__ wtsl, float* __restrict__ out) {
  __shared__ __align__(16) float sA[NJ*12];
  __shared__ float sW[256*NJ];          // 56320 B
  int b = blockIdx.y;
  int n0 = blockIdx.x*256;
  int cnt = min(256, NV - n0);
  for (int idx=threadIdx.x; idx<NJ*12; idx+=256) sA[idx] = arel[(size_t)b*NJ*12 + idx];
  int tot = cnt*NJ;
  for (int idx=threadIdx.x; idx<tot; idx+=256) sW[idx] = lw[(size_t)n0*NJ + idx];
  __syncthreads();
  int t = threadIdx.x, n = n0 + t;
  if (n >= NV) return;
  float T[12];
  #pragma unroll
  for (int e=0;e<12;e++) T[e]=0.f;
  const float* wp = sW + t*NJ;
  for (int j=0;j<NJ;j++){
    float wgt = wp[j];
    const float4* A4 = (const float4*)(sA + j*12);
    float4 a=A4[0], c=A4[1], d=A4[2];
    T[0]+=wgt*a.x; T[1]+=wgt*a.y; T[2] +=wgt*a.z; T[3] +=wgt*a.w;
    T[4]+=wgt*c.x; T[5]+=wgt*c.y; T[6] +=wgt*c.z; T[7] +=wgt*c.w;
    T[8]+=wgt*d.x; T[9]+=wgt*d.y; T[10]+=wgt*d.z; T[11]+=wgt*d.w;
  }
  float* op = out + ((size_t)b*NV + n)*3;
  float x=op[0], y=op[1], z=op[2];
  float tx=wtsl[b*3+0], ty=wtsl[b*3+1], tz=wtsl[b*3+2];
  op[0] = T[0]*x + T[1]*y + T[2] *z + T[3]  + tx;
  op[1] = T[4]*x + T[5]*y + T[6] *z + T[7]  + ty;
  op[2] = T[8]*x + T[9]*y + T[10]*z + T[11] + tz;
}

extern "C" void kernel_launch(void* const* d_in, const int* in_sizes, int n_in,
                              void* d_out, int out_size, void* d_ws, size_t ws_size,
                              hipStream_t stream) {
  const float* wrot   = (const float*)d_in[0];
  const float* wtsl   = (const float*)d_in[1];
  const float* bshape = (const float*)d_in[2];
  const float* bpose  = (const float*)d_in[3];
  const float* lhand  = (const float*)d_in[4];
  const float* rhand  = (const float*)d_in[5];
  const float* eshape = (const float*)d_in[6];
  const float* jaw    = (const float*)d_in[7];
  const float* leye   = (const float*)d_in[8];
  const float* reye   = (const float*)d_in[9];
  const float* vt     = (const float*)d_in[10];
  const float* sd     = (const float*)d_in[11];
  const float* ed     = (const float*)d_in[12];
  const float* pd     = (const float*)d_in[13];
  const float* jreg   = (const float*)d_in[14];
  const float* lw     = (const float*)d_in[15];
  float* out = (float*)d_out;

  // d_out verts region doubles as v_shaped / v_posed scratch (fp32, 1:1 layout)
  float* vsh  = out;                               // BATCH*VC floats
  float* jout = out + (size_t)BATCH*NV*3;          // BATCH*NJ*3 floats

  float* ws     = (float*)d_ws;                    // ~3.1 MB of scratch
  float* joints = ws;                                      // BATCH*NJ*3   = 42240
  float* chain  = joints + (size_t)BATCH*NJ*3;             // BATCH*NJ*12  = 168960
  float* arel   = chain  + (size_t)BATCH*NJ*12;            // BATCH*NJ*12  = 168960
  float* part   = arel   + (size_t)BATCH*NJ*12;            // BATCH*JCH*NJ*3 = 337920
  unsigned short* pfb = (unsigned short*)(part + (size_t)BATCH*JCH*NJ*3); // BATCH*KP u16

  k_vshaped       <<<dim3(41, BATCH), 256, 0, stream>>>(vt, sd, ed, bshape, eshape, vsh);
  k_posefeat      <<<dim3(BATCH),     512, 0, stream>>>(bpose, jaw, leye, reye, lhand, rhand, pfb);
  k_joints_partial<<<dim3(JCH, BATCH),256, 0, stream>>>(jreg, vsh, part);
  k_joints_reduce <<<dim3(BATCH),     256, 0, stream>>>(part, joints);
  k_chain         <<<dim3(4),          64, 0, stream>>>(wrot, bpose, jaw, leye, reye, lhand,
                                                        rhand, wtsl, joints, chain, arel, jout);
  k_vposed        <<<dim3((VC+BN-1)/BN), 256, 0, stream>>>(pd, pfb, vsh);
  k_verts         <<<dim3(41, BATCH), 256, 0, stream>>>(lw, arel, wtsl, out);
}

// Round 4
// 379.145 us; speedup vs baseline: 1.6620x; 1.5159x over previous
//
#include <hip/hip_runtime.h>
#include <stdint.h>

#define BATCH 256
#define NV 10475
#define NVP 10496        // NV padded to 164 tiles of 64
#define NJ 55
#define PB 486           // (NJ-1)*9
#define KS 506           // PB + 10 betas + 10 exprs
#define VC (NV*3)        // 31425
#define KP 512           // K padded to 16 chunks of 32
#define BKC 32
#define NCHUNK 16
#define BN 64
#define JCH 8
#define JCHUNK 1312      // 8*1312 >= NV

typedef short bf16x8 __attribute__((ext_vector_type(8)));
typedef float f32x4  __attribute__((ext_vector_type(4)));

__constant__ int c_parents[NJ] = {
  -1,0,0,0,1,2,3,4,5,6,7,8,9,9,9,12,13,14,16,17,18,19,15,15,15,
  20,25,26,20,28,29,20,31,32,20,34,35,20,37,38,21,40,41,21,43,44,
  21,46,47,21,49,50,21,52,53};

__device__ __forceinline__ unsigned short f2bf(float x){   // RNE fp32->bf16
  uint32_t u = __float_as_uint(x);
  uint32_t r = (u + 0x7fffu + ((u >> 16) & 1u)) >> 16;
  return (unsigned short)r;
}
__device__ __forceinline__ float bf2f(unsigned short h){
  return __uint_as_float(((uint32_t)h) << 16);
}

// ---------------- prep: lw -> bf16 hi/lo [NVP][64]; sd/ed -> fp32 [20][VC] --
__global__ __launch_bounds__(256) void k_prep(
    const float* __restrict__ lw, const float* __restrict__ sd,
    const float* __restrict__ ed, unsigned short* __restrict__ lwb,
    float* __restrict__ sdedT) {
  int bid = blockIdx.x;
  const int LWB_BLOCKS = (NVP*64)/256;     // 2624
  if (bid < LWB_BLOCKS) {
    int idx = bid*256 + threadIdx.x;       // n*64 + j
    int n = idx >> 6, j = idx & 63;
    float v = (n < NV && j < NJ) ? lw[(size_t)n*NJ + j] : 0.f;
    unsigned short hi = f2bf(v);
    float lo = v - bf2f(hi);
    lwb[idx] = hi;
    lwb[(size_t)NVP*64 + idx] = f2bf(lo);
  } else {
    int idx = (bid - LWB_BLOCKS)*256 + threadIdx.x;   // r*VC + col
    if (idx >= 20*VC) return;
    int r = idx / VC, col = idx - r*VC;
    int n = col/3, c = col - n*3;
    float v = (r < 10) ? sd[(size_t)n*30 + c*10 + r]
                       : ed[(size_t)n*30 + c*10 + (r-10)];
    sdedT[idx] = v;
  }
}

// ---------------- full_pose gather helper ----------------------------------
__device__ __forceinline__ const float* pose_src(int j, int b,
    const float* wrot, const float* bpose, const float* jaw, const float* leye,
    const float* reye, const float* lhand, const float* rhand) {
  if (j==0)  return wrot  + b*9;
  if (j<=21) return bpose + (b*21 + (j-1))*9;
  if (j==22) return jaw   + b*9;
  if (j==23) return leye  + b*9;
  if (j==24) return reye  + b*9;
  if (j<=39) return lhand + (b*15 + (j-25))*9;
  return rhand + (b*15 + (j-40))*9;
}

// ------- A-matrix for big GEMM: [pose_feature(486) | bs(10) | es(10) | 0] ---
__global__ __launch_bounds__(512) void k_posefeat(
    const float* __restrict__ bpose, const float* __restrict__ jaw,
    const float* __restrict__ leye, const float* __restrict__ reye,
    const float* __restrict__ lhand, const float* __restrict__ rhand,
    const float* __restrict__ bs, const float* __restrict__ es,
    unsigned short* __restrict__ pfb) {
  int b = blockIdx.x, t = threadIdx.x;     // t < 512
  unsigned short o = 0;
  if (t < PB){
    int jj = t/9, rc = t - jj*9;
    const float* rs = pose_src(jj+1, b, nullptr, bpose, jaw, leye, reye, lhand, rhand);
    float v = rs[rc];
    if (rc==0 || rc==4 || rc==8) v -= 1.0f;
    o = f2bf(v);
  } else if (t < 496){
    o = f2bf(bs[b*10 + (t-486)]);
  } else if (t < KS){
    o = f2bf(es[b*10 + (t-496)]);
  }
  pfb[(size_t)b*KP + t] = o;
}

// ---------------- JS = Jreg @ [sd | ed | vt] : per-(joint,chunk) partials ---
__global__ __launch_bounds__(256) void k_jsmall(
    const float* __restrict__ jreg, const float* __restrict__ sd,
    const float* __restrict__ ed, const float* __restrict__ vt,
    float* __restrict__ part) {
  int ch = blockIdx.x, j = blockIdx.y;
  int t = threadIdx.x;
  float acc[63];
  #pragma unroll
  for (int s=0;s<63;s++) acc[s]=0.f;
  int n0 = ch*JCHUNK, nend = min(n0+JCHUNK, NV);
  for (int n = n0 + t; n < nend; n += 256){
    float w = jreg[(size_t)j*NV + n];
    const float* sp = sd + (size_t)n*30;
    const float* ep = ed + (size_t)n*30;
    const float* vp = vt + (size_t)n*3;
    #pragma unroll
    for (int c=0;c<3;c++){
      #pragma unroll
      for (int q=0;q<10;q++){
        acc[c*21+q]    += w*sp[c*10+q];
        acc[c*21+10+q] += w*ep[c*10+q];
      }
      acc[c*21+20] += w*vp[c];
    }
  }
  #pragma unroll
  for (int s=0;s<63;s++){
    float a = acc[s];
    #pragma unroll
    for (int d=32; d>=1; d>>=1) a += __shfl_xor(a,d);
    acc[s]=a;
  }
  __shared__ float red[4][63];
  int w = t>>6, l = t&63;
  if (l==0){
    #pragma unroll
    for (int s=0;s<63;s++) red[w][s]=acc[s];
  }
  __syncthreads();
  if (t < 63){
    float a = red[0][t]+red[1][t]+red[2][t]+red[3][t];
    part[((size_t)j*JCH+ch)*63 + t] = a;
  }
}

// ---------------- joints[b][j][c] from JS partials + betas ------------------
__global__ __launch_bounds__(192) void k_joints2(
    const float* __restrict__ part, const float* __restrict__ bs,
    const float* __restrict__ es, float* __restrict__ joints) {
  int b = blockIdx.x, t = threadIdx.x;
  if (t >= NJ*3) return;
  int j = t/3, c = t - j*3;
  float S[21];
  #pragma unroll
  for (int q=0;q<21;q++) S[q]=0.f;
  for (int ch=0; ch<JCH; ch++){
    const float* p = part + ((size_t)j*JCH+ch)*63 + c*21;
    #pragma unroll
    for (int q=0;q<21;q++) S[q] += p[q];
  }
  float a = S[20];
  #pragma unroll
  for (int q=0;q<10;q++) a += S[q]*bs[b*10+q] + S[10+q]*es[b*10+q];
  joints[(size_t)b*NJ*3 + t] = a;
}

// ---------------- kinematic chain + A_rel(bf16 hi/lo) + joints_out ----------
__global__ __launch_bounds__(64) void k_chain(
    const float* __restrict__ wrot, const float* __restrict__ bpose,
    const float* __restrict__ jaw, const float* __restrict__ leye,
    const float* __restrict__ reye, const float* __restrict__ lhand,
    const float* __restrict__ rhand, const float* __restrict__ wtsl,
    const float* __restrict__ joints, float* __restrict__ chain,
    unsigned short* __restrict__ arelb, float* __restrict__ jout) {
  int b = blockIdx.x*64 + threadIdx.x;   // grid 4 x 64 = 256 batches
  const float* jb = joints + (size_t)b*NJ*3;
  for (int j=0;j<NJ;j++){
    const float* R = pose_src(j, b, wrot, bpose, jaw, leye, reye, lhand, rhand);
    int p = c_parents[j];
    float t0,t1,t2;
    if (p < 0){ t0=jb[0]; t1=jb[1]; t2=jb[2]; }
    else { t0=jb[j*3+0]-jb[p*3+0]; t1=jb[j*3+1]-jb[p*3+1]; t2=jb[j*3+2]-jb[p*3+2]; }
    float* Cj = chain + ((size_t)b*NJ+j)*12;
    if (p < 0){
      #pragma unroll
      for (int r=0;r<3;r++){
        Cj[r*4+0]=R[r*3+0]; Cj[r*4+1]=R[r*3+1]; Cj[r*4+2]=R[r*3+2];
      }
      Cj[3]=t0; Cj[7]=t1; Cj[11]=t2;
    } else {
      const float* Cp = chain + ((size_t)b*NJ+p)*12;
      float P[12];
      #pragma unroll
      for (int i=0;i<12;i++) P[i]=Cp[i];
      #pragma unroll
      for (int r=0;r<3;r++){
        float p0=P[r*4+0], p1=P[r*4+1], p2=P[r*4+2], p3=P[r*4+3];
        Cj[r*4+0] = p0*R[0]+p1*R[3]+p2*R[6];
        Cj[r*4+1] = p0*R[1]+p1*R[4]+p2*R[7];
        Cj[r*4+2] = p0*R[2]+p1*R[5]+p2*R[8];
        Cj[r*4+3] = p0*t0 + p1*t1 + p2*t2 + p3;
      }
    }
  }
  float wx=wtsl[b*3+0], wy=wtsl[b*3+1], wz=wtsl[b*3+2];
  unsigned short* ah = arelb + (size_t)(b*2+0)*16*64;
  unsigned short* al = arelb + (size_t)(b*2+1)*16*64;
  for (int j=0;j<NJ;j++){
    const float* C = chain + ((size_t)b*NJ+j)*12;
    float P[12];
    #pragma unroll
    for (int i=0;i<12;i++) P[i]=C[i];
    float j0=jb[j*3+0], j1=jb[j*3+1], j2=jb[j*3+2];
    #pragma unroll
    for (int r=0;r<3;r++){
      float A0=P[r*4+0], A1=P[r*4+1], A2=P[r*4+2];
      float A3=P[r*4+3] - (A0*j0 + A1*j1 + A2*j2);
      float Av[4] = {A0,A1,A2,A3};
      #pragma unroll
      for (int cc=0;cc<4;cc++){
        int e = r*4+cc;
        unsigned short hi = f2bf(Av[cc]);
        float lo = Av[cc] - bf2f(hi);
        ah[e*64 + j] = hi;
        al[e*64 + j] = f2bf(lo);
      }
    }
    jout[((size_t)b*NJ+j)*3+0]=P[3] +wx;
    jout[((size_t)b*NJ+j)*3+1]=P[7] +wy;
    jout[((size_t)b*NJ+j)*3+2]=P[11]+wz;
  }
  // zero-fill pads (re-poisoned every call, so do it every call)
  #pragma unroll
  for (int e=0;e<16;e++){
    for (int k=(e<12?NJ:0); k<64; k++){ ah[e*64+k]=0; al[e*64+k]=0; }
  }
}

// -------- v_posed = [pf|bs|es] @ [posedirs; sdT; edT] + vt  (bf16 MFMA) -----
// One block = 4 waves covers ALL 256 batches x 64 cols. Writes vsh directly.
__global__ __launch_bounds__(256) void k_vposed(
    const float* __restrict__ pd, const float* __restrict__ sdedT,
    const float* __restrict__ vt, const unsigned short* __restrict__ pfb,
    float* __restrict__ vsh) {
  __shared__ __align__(16) unsigned short sB[2][BN*40];  // B[n][k], stride 40
  const int tid  = threadIdx.x;
  const int w    = tid >> 6, lane = tid & 63;
  const int m16  = lane & 15, quad = lane >> 4;
  const int col0 = blockIdx.x * BN;

  f32x4 acc[4][4];
  #pragma unroll
  for (int i=0;i<4;i++)
    #pragma unroll
    for (int j=0;j<4;j++) acc[i][j] = (f32x4){0.f,0.f,0.f,0.f};

  // stage chunk 0 (rows 0..31: all posedirs)
  #pragma unroll
  for (int i=0;i<8;i++){
    int idx = tid + i*256;
    int k = idx >> 6, n = idx & 63;
    int cc = col0 + n;
    float v = (cc < VC) ? pd[(size_t)k*VC + cc] : 0.f;
    sB[0][n*40 + k] = f2bf(v);
  }

  for (int c=0; c<NCHUNK; c++){
    __syncthreads();
    const unsigned short* sBc = sB[c&1];
    const int k0 = c*BKC;
    bf16x8 a[4], bb[4];
    #pragma unroll
    for (int mi=0;mi<4;mi++){
      int row = w*64 + mi*16 + m16;
      a[mi] = *((const bf16x8*)(pfb + (size_t)row*KP + k0 + quad*8));
    }
    #pragma unroll
    for (int ni=0;ni<4;ni++)
      bb[ni] = *((const bf16x8*)(sBc + (ni*16 + m16)*40 + quad*8));
    #pragma unroll
    for (int mi=0;mi<4;mi++)
      #pragma unroll
      for (int ni=0;ni<4;ni++)
        acc[mi][ni] = __builtin_amdgcn_mfma_f32_16x16x32_bf16(
                          a[mi], bb[ni], acc[mi][ni], 0, 0, 0);
    if (c+1 < NCHUNK){
      unsigned short* sBn = sB[(c+1)&1];
      const int k0n = (c+1)*BKC;
      #pragma unroll
      for (int i=0;i<8;i++){
        int idx = tid + i*256;
        int k = idx >> 6, n = idx & 63;
        int kk = k0n + k, cc = col0 + n;
        float v = 0.f;
        if (cc < VC){
          if (kk < PB)      v = pd[(size_t)kk*VC + cc];
          else if (kk < KS) v = sdedT[(size_t)(kk-PB)*VC + cc];
        }
        sBn[n*40 + k] = f2bf(v);
      }
    }
  }
  // epilogue: vsh[row][col] = acc + v_template[col]
  #pragma unroll
  for (int mi=0;mi<4;mi++){
    int rbase = w*64 + mi*16 + quad*4;
    #pragma unroll
    for (int ni=0;ni<4;ni++){
      int col = col0 + ni*16 + m16;
      if (col < VC){
        float vtc = vt[col];
        #pragma unroll
        for (int r=0;r<4;r++)
          vsh[(size_t)(rbase + r)*VC + col] = acc[mi][ni][r] + vtc;
      }
    }
  }
}

// -------- skinning via MFMA: T(64v x 16e) = lw(64v x 64j) @ arelT(64j x 16e)
// block: 64 verts x 16 batches; hi/lo split on both operands (3 MFMAs).
__global__ __launch_bounds__(256) void k_verts(
    const unsigned short* __restrict__ lwb, const unsigned short* __restrict__ arelb,
    const float* __restrict__ wtsl, float* __restrict__ out) {
  __shared__ float sT[16*64*17];           // 69632 B, stride 17 (coprime 32)
  const int tid = threadIdx.x, w = tid >> 6, lane = tid & 63;
  const int m16 = lane & 15, quad = lane >> 4;
  const int n0 = blockIdx.x*64;
  const int b0 = blockIdx.y*16;

  // A fragments (lw): 4 vert-tiles x 2 k-chunks x {hi,lo}
  bf16x8 ahh[4][2], all[4][2];
  #pragma unroll
  for (int t4=0;t4<4;t4++){
    int row = n0 + t4*16 + m16;
    #pragma unroll
    for (int kc=0;kc<2;kc++){
      ahh[t4][kc] = *((const bf16x8*)(lwb + (size_t)row*64 + kc*32 + quad*8));
      all[t4][kc] = *((const bf16x8*)(lwb + (size_t)NVP*64 + (size_t)row*64 + kc*32 + quad*8));
    }
  }
  for (int bi=0; bi<4; bi++){
    int b = b0 + w*4 + bi;
    bf16x8 bh[2], bl[2];
    #pragma unroll
    for (int kc=0;kc<2;kc++){
      bh[kc] = *((const bf16x8*)(arelb + ((size_t)(b*2+0)*16 + m16)*64 + kc*32 + quad*8));
      bl[kc] = *((const bf16x8*)(arelb + ((size_t)(b*2+1)*16 + m16)*64 + kc*32 + quad*8));
    }
    f32x4 acc[4];
    #pragma unroll
    for (int t4=0;t4<4;t4++) acc[t4] = (f32x4){0.f,0.f,0.f,0.f};
    #pragma unroll
    for (int t4=0;t4<4;t4++)
      #pragma unroll
      for (int kc=0;kc<2;kc++){
        acc[t4] = __builtin_amdgcn_mfma_f32_16x16x32_bf16(ahh[t4][kc], bh[kc], acc[t4], 0,0,0);
        acc[t4] = __builtin_amdgcn_mfma_f32_16x16x32_bf16(all[t4][kc], bh[kc], acc[t4], 0,0,0);
        acc[t4] = __builtin_amdgcn_mfma_f32_16x16x32_bf16(ahh[t4][kc], bl[kc], acc[t4], 0,0,0);
      }
    if (m16 < 12){
      int slot = w*4 + bi;
      #pragma unroll
      for (int t4=0;t4<4;t4++){
        #pragma unroll
        for (int r=0;r<4;r++){
          int vert = t4*16 + quad*4 + r;
          sT[(slot*64 + vert)*17 + m16] = acc[t4][r];
        }
      }
    }
  }
  __syncthreads();
  // apply T to v_posed (in place on out's verts region)
  #pragma unroll
  for (int it=0; it<4; it++){
    int pid = it*256 + tid;
    int bb = pid >> 6, v = pid & 63;
    int n = n0 + v;
    if (n >= NV) continue;
    int b = b0 + bb;
    const float* Tp = &sT[(bb*64 + v)*17];
    float T[12];
    #pragma unroll
    for (int e=0;e<12;e++) T[e] = Tp[e];
    float* op = out + ((size_t)b*NV + n)*3;
    float x=op[0], y=op[1], z=op[2];
    float tx=wtsl[b*3+0], ty=wtsl[b*3+1], tz=wtsl[b*3+2];
    op[0] = T[0]*x + T[1]*y + T[2] *z + T[3]  + tx;
    op[1] = T[4]*x + T[5]*y + T[6] *z + T[7]  + ty;
    op[2] = T[8]*x + T[9]*y + T[10]*z + T[11] + tz;
  }
}

extern "C" void kernel_launch(void* const* d_in, const int* in_sizes, int n_in,
                              void* d_out, int out_size, void* d_ws, size_t ws_size,
                              hipStream_t stream) {
  const float* wrot   = (const float*)d_in[0];
  const float* wtsl   = (const float*)d_in[1];
  const float* bshape = (const float*)d_in[2];
  const float* bpose  = (const float*)d_in[3];
  const float* lhand  = (const float*)d_in[4];
  const float* rhand  = (const float*)d_in[5];
  const float* eshape = (const float*)d_in[6];
  const float* jaw    = (const float*)d_in[7];
  const float* leye   = (const float*)d_in[8];
  const float* reye   = (const float*)d_in[9];
  const float* vt     = (const float*)d_in[10];
  const float* sd     = (const float*)d_in[11];
  const float* ed     = (const float*)d_in[12];
  const float* pd     = (const float*)d_in[13];
  const float* jreg   = (const float*)d_in[14];
  const float* lw     = (const float*)d_in[15];
  float* out = (float*)d_out;

  float* vsh  = out;                               // verts region = v_posed scratch
  float* jout = out + (size_t)BATCH*NV*3;

  float* ws     = (float*)d_ws;                    // ~7.5 MB total
  float* joints = ws;                                      // 256*165   = 42240
  float* part   = joints + (size_t)BATCH*NJ*3;             // 55*8*63   = 27720
  float* chain  = part   + (size_t)NJ*JCH*63;              // 256*660   = 168960
  float* sdedT  = chain  + (size_t)BATCH*NJ*12;            // 20*VC     = 628500
  unsigned short* pfb   = (unsigned short*)(sdedT + (size_t)20*VC);   // 256*512
  unsigned short* lwb   = pfb + (size_t)BATCH*KP;                     // 2*NVP*64
  unsigned short* arelb = lwb + (size_t)2*NVP*64;                     // 256*2*16*64

  const int PREP_BLOCKS = (NVP*64)/256 + (20*VC + 255)/256;   // 2624 + 2456

  k_prep    <<<PREP_BLOCKS, 256, 0, stream>>>(lw, sd, ed, lwb, sdedT);
  k_posefeat<<<BATCH, 512, 0, stream>>>(bpose, jaw, leye, reye, lhand, rhand,
                                        bshape, eshape, pfb);
  k_jsmall  <<<dim3(JCH, NJ), 256, 0, stream>>>(jreg, sd, ed, vt, part);
  k_joints2 <<<BATCH, 192, 0, stream>>>(part, bshape, eshape, joints);
  k_chain   <<<4, 64, 0, stream>>>(wrot, bpose, jaw, leye, reye, lhand, rhand,
                                   wtsl, joints, chain, arelb, jout);
  k_vposed  <<<(VC+BN-1)/BN, 256, 0, stream>>>(pd, sdedT, vt, pfb, vsh);
  k_verts   <<<dim3(NVP/64, 16), 256, 0, stream>>>(lwb, arelb, wtsl, out);
}

// Round 5
// 271.137 us; speedup vs baseline: 2.3241x; 1.3983x over previous
//
#include <hip/hip_runtime.h>
#include <stdint.h>

#define BATCH 256
#define NV 10475
#define NVP 10496        // NV padded to 164 tiles of 64
#define NJ 55
#define PB 486           // (NJ-1)*9
#define KS 506           // PB + 10 betas + 10 exprs
#define VC (NV*3)        // 31425
#define KP 512           // K padded to 16 chunks of 32
#define BKC 32
#define NCHUNK 16
#define BN 64
#define JCH 8
#define JCHUNK 1312      // 8*1312 >= NV

typedef short bf16x8 __attribute__((ext_vector_type(8)));
typedef float f32x4  __attribute__((ext_vector_type(4)));

__constant__ int c_parents[NJ] = {
  -1,0,0,0,1,2,3,4,5,6,7,8,9,9,9,12,13,14,16,17,18,19,15,15,15,
  20,25,26,20,28,29,20,31,32,20,34,35,20,37,38,21,40,41,21,43,44,
  21,46,47,21,49,50,21,52,53};

// tree depth of each joint (max 10)
__constant__ int c_depth[NJ] = {
  0,1,1,1,2,2,2,3,3,3,4,4,4,4,4,5,5,5,6,6,7,7,6,6,6,
  8,9,10,8,9,10,8,9,10,8,9,10,8,9,10,
  8,9,10,8,9,10,8,9,10,8,9,10,8,9,10};

__device__ __forceinline__ unsigned short f2bf(float x){   // RNE fp32->bf16
  uint32_t u = __float_as_uint(x);
  uint32_t r = (u + 0x7fffu + ((u >> 16) & 1u)) >> 16;
  return (unsigned short)r;
}
__device__ __forceinline__ float bf2f(unsigned short h){
  return __uint_as_float(((uint32_t)h) << 16);
}

// ---------------- prep: lw -> bf16 hi/lo [NVP][64]; sd/ed -> fp32 [20][VC] --
__global__ __launch_bounds__(256) void k_prep(
    const float* __restrict__ lw, const float* __restrict__ sd,
    const float* __restrict__ ed, unsigned short* __restrict__ lwb,
    float* __restrict__ sdedT) {
  int bid = blockIdx.x;
  const int LWB_BLOCKS = (NVP*64)/256;     // 2624
  if (bid < LWB_BLOCKS) {
    int idx = bid*256 + threadIdx.x;       // n*64 + j
    int n = idx >> 6, j = idx & 63;
    float v = (n < NV && j < NJ) ? lw[(size_t)n*NJ + j] : 0.f;
    unsigned short hi = f2bf(v);
    float lo = v - bf2f(hi);
    lwb[idx] = hi;
    lwb[(size_t)NVP*64 + idx] = f2bf(lo);
  } else {
    int idx = (bid - LWB_BLOCKS)*256 + threadIdx.x;   // r*VC + col
    if (idx >= 20*VC) return;
    int r = idx / VC, col = idx - r*VC;
    int n = col/3, c = col - n*3;
    float v = (r < 10) ? sd[(size_t)n*30 + c*10 + r]
                       : ed[(size_t)n*30 + c*10 + (r-10)];
    sdedT[idx] = v;
  }
}

// ---------------- full_pose gather helper ----------------------------------
__device__ __forceinline__ const float* pose_src(int j, int b,
    const float* wrot, const float* bpose, const float* jaw, const float* leye,
    const float* reye, const float* lhand, const float* rhand) {
  if (j==0)  return wrot  + b*9;
  if (j<=21) return bpose + (b*21 + (j-1))*9;
  if (j==22) return jaw   + b*9;
  if (j==23) return leye  + b*9;
  if (j==24) return reye  + b*9;
  if (j<=39) return lhand + (b*15 + (j-25))*9;
  return rhand + (b*15 + (j-40))*9;
}

// ------- A-matrix for big GEMM: [pose_feature(486) | bs(10) | es(10) | 0] ---
__global__ __launch_bounds__(512) void k_posefeat(
    const float* __restrict__ bpose, const float* __restrict__ jaw,
    const float* __restrict__ leye, const float* __restrict__ reye,
    const float* __restrict__ lhand, const float* __restrict__ rhand,
    const float* __restrict__ bs, const float* __restrict__ es,
    unsigned short* __restrict__ pfb) {
  int b = blockIdx.x, t = threadIdx.x;     // t < 512
  unsigned short o = 0;
  if (t < PB){
    int jj = t/9, rc = t - jj*9;
    const float* rs = pose_src(jj+1, b, nullptr, bpose, jaw, leye, reye, lhand, rhand);
    float v = rs[rc];
    if (rc==0 || rc==4 || rc==8) v -= 1.0f;
    o = f2bf(v);
  } else if (t < 496){
    o = f2bf(bs[b*10 + (t-486)]);
  } else if (t < KS){
    o = f2bf(es[b*10 + (t-496)]);
  }
  pfb[(size_t)b*KP + t] = o;
}

// ---------------- JS = Jreg @ [sd | ed | vt] : per-(joint,chunk) partials ---
__global__ __launch_bounds__(256) void k_jsmall(
    const float* __restrict__ jreg, const float* __restrict__ sd,
    const float* __restrict__ ed, const float* __restrict__ vt,
    float* __restrict__ part) {
  int ch = blockIdx.x, j = blockIdx.y;
  int t = threadIdx.x;
  float acc[63];
  #pragma unroll
  for (int s=0;s<63;s++) acc[s]=0.f;
  int n0 = ch*JCHUNK, nend = min(n0+JCHUNK, NV);
  for (int n = n0 + t; n < nend; n += 256){
    float w = jreg[(size_t)j*NV + n];
    const float* sp = sd + (size_t)n*30;
    const float* ep = ed + (size_t)n*30;
    const float* vp = vt + (size_t)n*3;
    #pragma unroll
    for (int c=0;c<3;c++){
      #pragma unroll
      for (int q=0;q<10;q++){
        acc[c*21+q]    += w*sp[c*10+q];
        acc[c*21+10+q] += w*ep[c*10+q];
      }
      acc[c*21+20] += w*vp[c];
    }
  }
  #pragma unroll
  for (int s=0;s<63;s++){
    float a = acc[s];
    #pragma unroll
    for (int d=32; d>=1; d>>=1) a += __shfl_xor(a,d);
    acc[s]=a;
  }
  __shared__ float red[4][63];
  int w = t>>6, l = t&63;
  if (l==0){
    #pragma unroll
    for (int s=0;s<63;s++) red[w][s]=acc[s];
  }
  __syncthreads();
  if (t < 63){
    float a = red[0][t]+red[1][t]+red[2][t]+red[3][t];
    part[((size_t)j*JCH+ch)*63 + t] = a;
  }
}

// ---------------- joints[b][j][c] from JS partials + betas ------------------
__global__ __launch_bounds__(192) void k_joints2(
    const float* __restrict__ part, const float* __restrict__ bs,
    const float* __restrict__ es, float* __restrict__ joints) {
  int b = blockIdx.x, t = threadIdx.x;
  if (t >= NJ*3) return;
  int j = t/3, c = t - j*3;
  float S[21];
  #pragma unroll
  for (int q=0;q<21;q++) S[q]=0.f;
  for (int ch=0; ch<JCH; ch++){
    const float* p = part + ((size_t)j*JCH+ch)*63 + c*21;
    #pragma unroll
    for (int q=0;q<21;q++) S[q] += p[q];
  }
  float a = S[20];
  #pragma unroll
  for (int q=0;q<10;q++) a += S[q]*bs[b*10+q] + S[10+q]*es[b*10+q];
  joints[(size_t)b*NJ*3 + t] = a;
}

// ------- kinematic chain via wave-level tree scan (lane j = joint j) --------
// One wave per batch; chain matrices live in registers; parents via __shfl.
__global__ __launch_bounds__(256) void k_chain(
    const float* __restrict__ wrot, const float* __restrict__ bpose,
    const float* __restrict__ jaw, const float* __restrict__ leye,
    const float* __restrict__ reye, const float* __restrict__ lhand,
    const float* __restrict__ rhand, const float* __restrict__ wtsl,
    const float* __restrict__ joints,
    unsigned short* __restrict__ arelb, float* __restrict__ jout) {
  const int w = threadIdx.x >> 6, lane = threadIdx.x & 63;
  const int b = blockIdx.x*4 + w;
  const int j = lane;
  const bool act = (j < NJ);

  // local rotation
  float R[9] = {1.f,0.f,0.f, 0.f,1.f,0.f, 0.f,0.f,1.f};
  if (act){
    const float* rs = pose_src(j, b, wrot, bpose, jaw, leye, reye, lhand, rhand);
    #pragma unroll
    for (int i=0;i<9;i++) R[i]=rs[i];
  }
  // joint position (lane-resident), parent via shuffle
  float jx=0.f, jy=0.f, jz=0.f;
  if (act){
    const float* jb = joints + (size_t)b*NJ*3 + j*3;
    jx=jb[0]; jy=jb[1]; jz=jb[2];
  }
  int par = act ? c_parents[j] : 0;
  if (par < 0) par = 0;
  float px = __shfl(jx, par), py = __shfl(jy, par), pz = __shfl(jz, par);
  float t0, t1, t2;
  if (j == 0){ t0=jx; t1=jy; t2=jz; }
  else       { t0=jx-px; t1=jy-py; t2=jz-pz; }

  // M starts as local [R|t]; becomes global at round == depth
  float M[12];
  #pragma unroll
  for (int r=0;r<3;r++){
    M[r*4+0]=R[r*3+0]; M[r*4+1]=R[r*3+1]; M[r*4+2]=R[r*3+2]; M[r*4+3]= (r==0?t0:(r==1?t1:t2));
  }
  int dep = act ? c_depth[j] : 99;

  #pragma unroll
  for (int L=1; L<=10; L++){
    float pm[12];
    #pragma unroll
    for (int i=0;i<12;i++) pm[i] = __shfl(M[i], par);   // exec-uniform
    if (dep == L){
      #pragma unroll
      for (int r=0;r<3;r++){
        float p0=pm[r*4+0], p1=pm[r*4+1], p2=pm[r*4+2], p3=pm[r*4+3];
        M[r*4+0] = p0*R[0]+p1*R[3]+p2*R[6];
        M[r*4+1] = p0*R[1]+p1*R[4]+p2*R[7];
        M[r*4+2] = p0*R[2]+p1*R[5]+p2*R[8];
        M[r*4+3] = p0*t0 + p1*t1 + p2*t2 + p3;
      }
    }
  }

  float wx=wtsl[b*3+0], wy=wtsl[b*3+1], wz=wtsl[b*3+2];
  if (act){
    jout[((size_t)b*NJ+j)*3+0] = M[3]  + wx;
    jout[((size_t)b*NJ+j)*3+1] = M[7]  + wy;
    jout[((size_t)b*NJ+j)*3+2] = M[11] + wz;
  }
  // A_rel with t-correction; bf16 hi/lo split; pads (lanes>=55, e>=12) zeroed
  float A[12];
  #pragma unroll
  for (int r=0;r<3;r++){
    A[r*4+0]=M[r*4+0]; A[r*4+1]=M[r*4+1]; A[r*4+2]=M[r*4+2];
    A[r*4+3]=M[r*4+3] - (M[r*4+0]*jx + M[r*4+1]*jy + M[r*4+2]*jz);
  }
  unsigned short* ah = arelb + (size_t)(b*2+0)*16*64;
  unsigned short* al = arelb + (size_t)(b*2+1)*16*64;
  #pragma unroll
  for (int e=0;e<16;e++){
    float v = (e < 12 && act) ? A[e] : 0.f;
    unsigned short hi = f2bf(v);
    float lo = v - bf2f(hi);
    ah[e*64 + j] = hi;                 // contiguous across lanes per e
    al[e*64 + j] = f2bf(lo);
  }
}

// -------- v_posed = [pf|bs|es] @ [posedirs; sdT; edT] + vt  (bf16 MFMA) -----
// One block = 4 waves covers ALL 256 batches x 64 cols. Writes vsh directly.
__global__ __launch_bounds__(256) void k_vposed(
    const float* __restrict__ pd, const float* __restrict__ sdedT,
    const float* __restrict__ vt, const unsigned short* __restrict__ pfb,
    float* __restrict__ vsh) {
  __shared__ __align__(16) unsigned short sB[2][BN*40];  // B[n][k], stride 40
  const int tid  = threadIdx.x;
  const int w    = tid >> 6, lane = tid & 63;
  const int m16  = lane & 15, quad = lane >> 4;
  const int col0 = blockIdx.x * BN;

  f32x4 acc[4][4];
  #pragma unroll
  for (int i=0;i<4;i++)
    #pragma unroll
    for (int j=0;j<4;j++) acc[i][j] = (f32x4){0.f,0.f,0.f,0.f};

  // stage chunk 0 (rows 0..31: all posedirs)
  #pragma unroll
  for (int i=0;i<8;i++){
    int idx = tid + i*256;
    int k = idx >> 6, n = idx & 63;
    int cc = col0 + n;
    float v = (cc < VC) ? pd[(size_t)k*VC + cc] : 0.f;
    sB[0][n*40 + k] = f2bf(v);
  }

  for (int c=0; c<NCHUNK; c++){
    __syncthreads();
    const unsigned short* sBc = sB[c&1];
    const int k0 = c*BKC;
    bf16x8 a[4], bb[4];
    #pragma unroll
    for (int mi=0;mi<4;mi++){
      int row = w*64 + mi*16 + m16;
      a[mi] = *((const bf16x8*)(pfb + (size_t)row*KP + k0 + quad*8));
    }
    #pragma unroll
    for (int ni=0;ni<4;ni++)
      bb[ni] = *((const bf16x8*)(sBc + (ni*16 + m16)*40 + quad*8));
    #pragma unroll
    for (int mi=0;mi<4;mi++)
      #pragma unroll
      for (int ni=0;ni<4;ni++)
        acc[mi][ni] = __builtin_amdgcn_mfma_f32_16x16x32_bf16(
                          a[mi], bb[ni], acc[mi][ni], 0, 0, 0);
    if (c+1 < NCHUNK){
      unsigned short* sBn = sB[(c+1)&1];
      const int k0n = (c+1)*BKC;
      #pragma unroll
      for (int i=0;i<8;i++){
        int idx = tid + i*256;
        int k = idx >> 6, n = idx & 63;
        int kk = k0n + k, cc = col0 + n;
        float v = 0.f;
        if (cc < VC){
          if (kk < PB)      v = pd[(size_t)kk*VC + cc];
          else if (kk < KS) v = sdedT[(size_t)(kk-PB)*VC + cc];
        }
        sBn[n*40 + k] = f2bf(v);
      }
    }
  }
  // epilogue: vsh[row][col] = acc + v_template[col]
  #pragma unroll
  for (int mi=0;mi<4;mi++){
    int rbase = w*64 + mi*16 + quad*4;
    #pragma unroll
    for (int ni=0;ni<4;ni++){
      int col = col0 + ni*16 + m16;
      if (col < VC){
        float vtc = vt[col];
        #pragma unroll
        for (int r=0;r<4;r++)
          vsh[(size_t)(rbase + r)*VC + col] = acc[mi][ni][r] + vtc;
      }
    }
  }
}

// -------- skinning via MFMA: T(64v x 16e) = lw(64v x 64j) @ arelT(64j x 16e)
// block: 64 verts x 16 batches; hi/lo split on both operands (3 MFMAs).
__global__ __launch_bounds__(256) void k_verts(
    const unsigned short* __restrict__ lwb, const unsigned short* __restrict__ arelb,
    const float* __restrict__ wtsl, float* __restrict__ out) {
  __shared__ float sT[16*64*17];           // 69632 B, stride 17 (coprime 32)
  const int tid = threadIdx.x, w = tid >> 6, lane = tid & 63;
  const int m16 = lane & 15, quad = lane >> 4;
  const int n0 = blockIdx.x*64;
  const int b0 = blockIdx.y*16;

  // A fragments (lw): 4 vert-tiles x 2 k-chunks x {hi,lo}
  bf16x8 ahh[4][2], all[4][2];
  #pragma unroll
  for (int t4=0;t4<4;t4++){
    int row = n0 + t4*16 + m16;
    #pragma unroll
    for (int kc=0;kc<2;kc++){
      ahh[t4][kc] = *((const bf16x8*)(lwb + (size_t)row*64 + kc*32 + quad*8));
      all[t4][kc] = *((const bf16x8*)(lwb + (size_t)NVP*64 + (size_t)row*64 + kc*32 + quad*8));
    }
  }
  for (int bi=0; bi<4; bi++){
    int b = b0 + w*4 + bi;
    bf16x8 bh[2], bl[2];
    #pragma unroll
    for (int kc=0;kc<2;kc++){
      bh[kc] = *((const bf16x8*)(arelb + ((size_t)(b*2+0)*16 + m16)*64 + kc*32 + quad*8));
      bl[kc] = *((const bf16x8*)(arelb + ((size_t)(b*2+1)*16 + m16)*64 + kc*32 + quad*8));
    }
    f32x4 acc[4];
    #pragma unroll
    for (int t4=0;t4<4;t4++) acc[t4] = (f32x4){0.f,0.f,0.f,0.f};
    #pragma unroll
    for (int t4=0;t4<4;t4++)
      #pragma unroll
      for (int kc=0;kc<2;kc++){
        acc[t4] = __builtin_amdgcn_mfma_f32_16x16x32_bf16(ahh[t4][kc], bh[kc], acc[t4], 0,0,0);
        acc[t4] = __builtin_amdgcn_mfma_f32_16x16x32_bf16(all[t4][kc], bh[kc], acc[t4], 0,0,0);
        acc[t4] = __builtin_amdgcn_mfma_f32_16x16x32_bf16(ahh[t4][kc], bl[kc], acc[t4], 0,0,0);
      }
    if (m16 < 12){
      int slot = w*4 + bi;
      #pragma unroll
      for (int t4=0;t4<4;t4++){
        #pragma unroll
        for (int r=0;r<4;r++){
          int vert = t4*16 + quad*4 + r;
          sT[(slot*64 + vert)*17 + m16] = acc[t4][r];
        }
      }
    }
  }
  __syncthreads();
  // apply T to v_posed (in place on out's verts region)
  #pragma unroll
  for (int it=0; it<4; it++){
    int pid = it*256 + tid;
    int bb = pid >> 6, v = pid & 63;
    int n = n0 + v;
    if (n >= NV) continue;
    int b = b0 + bb;
    const float* Tp = &sT[(bb*64 + v)*17];
    float T[12];
    #pragma unroll
    for (int e=0;e<12;e++) T[e] = Tp[e];
    float* op = out + ((size_t)b*NV + n)*3;
    float x=op[0], y=op[1], z=op[2];
    float tx=wtsl[b*3+0], ty=wtsl[b*3+1], tz=wtsl[b*3+2];
    op[0] = T[0]*x + T[1]*y + T[2] *z + T[3]  + tx;
    op[1] = T[4]*x + T[5]*y + T[6] *z + T[7]  + ty;
    op[2] = T[8]*x + T[9]*y + T[10]*z + T[11] + tz;
  }
}

extern "C" void kernel_launch(void* const* d_in, const int* in_sizes, int n_in,
                              void* d_out, int out_size, void* d_ws, size_t ws_size,
                              hipStream_t stream) {
  const float* wrot   = (const float*)d_in[0];
  const float* wtsl   = (const float*)d_in[1];
  const float* bshape = (const float*)d_in[2];
  const float* bpose  = (const float*)d_in[3];
  const float* lhand  = (const float*)d_in[4];
  const float* rhand  = (const float*)d_in[5];
  const float* eshape = (const float*)d_in[6];
  const float* jaw    = (const float*)d_in[7];
  const float* leye   = (const float*)d_in[8];
  const float* reye   = (const float*)d_in[9];
  const float* vt     = (const float*)d_in[10];
  const float* sd     = (const float*)d_in[11];
  const float* ed     = (const float*)d_in[12];
  const float* pd     = (const float*)d_in[13];
  const float* jreg   = (const float*)d_in[14];
  const float* lw     = (const float*)d_in[15];
  float* out = (float*)d_out;

  float* vsh  = out;                               // verts region = v_posed scratch
  float* jout = out + (size_t)BATCH*NV*3;

  float* ws     = (float*)d_ws;                    // ~7 MB total
  float* joints = ws;                                      // 256*165   = 42240
  float* part   = joints + (size_t)BATCH*NJ*3;             // 55*8*63   = 27720
  float* sdedT  = part   + (size_t)NJ*JCH*63;              // 20*VC     = 628500
  unsigned short* pfb   = (unsigned short*)(sdedT + (size_t)20*VC);   // 256*512
  unsigned short* lwb   = pfb + (size_t)BATCH*KP;                     // 2*NVP*64
  unsigned short* arelb = lwb + (size_t)2*NVP*64;                     // 256*2*16*64

  const int PREP_BLOCKS = (NVP*64)/256 + (20*VC + 255)/256;   // 2624 + 2456

  k_prep    <<<PREP_BLOCKS, 256, 0, stream>>>(lw, sd, ed, lwb, sdedT);
  k_posefeat<<<BATCH, 512, 0, stream>>>(bpose, jaw, leye, reye, lhand, rhand,
                                        bshape, eshape, pfb);
  k_jsmall  <<<dim3(JCH, NJ), 256, 0, stream>>>(jreg, sd, ed, vt, part);
  k_joints2 <<<BATCH, 192, 0, stream>>>(part, bshape, eshape, joints);
  k_chain   <<<64, 256, 0, stream>>>(wrot, bpose, jaw, leye, reye, lhand, rhand,
                                     wtsl, joints, arelb, jout);
  k_vposed  <<<(VC+BN-1)/BN, 256, 0, stream>>>(pd, sdedT, vt, pfb, vsh);
  k_verts   <<<dim3(NVP/64, 16), 256, 0, stream>>>(lwb, arelb, wtsl, out);
}

// Round 6
// 255.374 us; speedup vs baseline: 2.4676x; 1.0617x over previous
//
#include <hip/hip_runtime.h>
#include <stdint.h>

#define BATCH 256
#define NV 10475
#define NVP 10496        // NV padded to 164 tiles of 64
#define NJ 55
#define PB 486           // (NJ-1)*9
#define KS 506           // PB + 10 betas + 10 exprs
#define VC (NV*3)        // 31425
#define KP 512           // K padded to 16 chunks of 32
#define BKC 32
#define NCHUNK 16
#define BN 64
#define JCH 8
#define JCHUNK 1312      // 8*1312 >= NV

typedef short bf16x8 __attribute__((ext_vector_type(8)));
typedef float f32x4  __attribute__((ext_vector_type(4)));

__constant__ int c_parents[NJ] = {
  -1,0,0,0,1,2,3,4,5,6,7,8,9,9,9,12,13,14,16,17,18,19,15,15,15,
  20,25,26,20,28,29,20,31,32,20,34,35,20,37,38,21,40,41,21,43,44,
  21,46,47,21,49,50,21,52,53};

// tree depth of each joint (max 10)
__constant__ int c_depth[NJ] = {
  0,1,1,1,2,2,2,3,3,3,4,4,4,4,4,5,5,5,6,6,7,7,6,6,6,
  8,9,10,8,9,10,8,9,10,8,9,10,8,9,10,
  8,9,10,8,9,10,8,9,10,8,9,10,8,9,10};

__device__ __forceinline__ unsigned short f2bf(float x){   // RNE fp32->bf16
  uint32_t u = __float_as_uint(x);
  uint32_t r = (u + 0x7fffu + ((u >> 16) & 1u)) >> 16;
  return (unsigned short)r;
}
__device__ __forceinline__ float bf2f(unsigned short h){
  return __uint_as_float(((uint32_t)h) << 16);
}

// ---------------- prep: lw -> bf16 hi/lo [NVP][64]; sd/ed -> fp32 [20][VC] --
__global__ __launch_bounds__(256) void k_prep(
    const float* __restrict__ lw, const float* __restrict__ sd,
    const float* __restrict__ ed, unsigned short* __restrict__ lwb,
    float* __restrict__ sdedT) {
  int bid = blockIdx.x;
  const int LWB_BLOCKS = (NVP*64)/256;     // 2624
  if (bid < LWB_BLOCKS) {
    int idx = bid*256 + threadIdx.x;       // n*64 + j
    int n = idx >> 6, j = idx & 63;
    float v = (n < NV && j < NJ) ? lw[(size_t)n*NJ + j] : 0.f;
    unsigned short hi = f2bf(v);
    float lo = v - bf2f(hi);
    lwb[idx] = hi;
    lwb[(size_t)NVP*64 + idx] = f2bf(lo);
  } else {
    int idx = (bid - LWB_BLOCKS)*256 + threadIdx.x;   // r*VC + col
    if (idx >= 20*VC) return;
    int r = idx / VC, col = idx - r*VC;
    int n = col/3, c = col - n*3;
    float v = (r < 10) ? sd[(size_t)n*30 + c*10 + r]
                       : ed[(size_t)n*30 + c*10 + (r-10)];
    sdedT[idx] = v;
  }
}

// ---------------- full_pose gather helper ----------------------------------
__device__ __forceinline__ const float* pose_src(int j, int b,
    const float* wrot, const float* bpose, const float* jaw, const float* leye,
    const float* reye, const float* lhand, const float* rhand) {
  if (j==0)  return wrot  + b*9;
  if (j<=21) return bpose + (b*21 + (j-1))*9;
  if (j==22) return jaw   + b*9;
  if (j==23) return leye  + b*9;
  if (j==24) return reye  + b*9;
  if (j<=39) return lhand + (b*15 + (j-25))*9;
  return rhand + (b*15 + (j-40))*9;
}

// ------- A-matrix for big GEMM: [pose_feature(486) | bs(10) | es(10) | 0] ---
__global__ __launch_bounds__(512) void k_posefeat(
    const float* __restrict__ bpose, const float* __restrict__ jaw,
    const float* __restrict__ leye, const float* __restrict__ reye,
    const float* __restrict__ lhand, const float* __restrict__ rhand,
    const float* __restrict__ bs, const float* __restrict__ es,
    unsigned short* __restrict__ pfb) {
  int b = blockIdx.x, t = threadIdx.x;     // t < 512
  unsigned short o = 0;
  if (t < PB){
    int jj = t/9, rc = t - jj*9;
    const float* rs = pose_src(jj+1, b, nullptr, bpose, jaw, leye, reye, lhand, rhand);
    float v = rs[rc];
    if (rc==0 || rc==4 || rc==8) v -= 1.0f;
    o = f2bf(v);
  } else if (t < 496){
    o = f2bf(bs[b*10 + (t-486)]);
  } else if (t < KS){
    o = f2bf(es[b*10 + (t-496)]);
  }
  pfb[(size_t)b*KP + t] = o;
}

// ---------------- JS = Jreg @ [sd | ed | vt] : per-(joint,chunk) partials ---
__global__ __launch_bounds__(256) void k_jsmall(
    const float* __restrict__ jreg, const float* __restrict__ sd,
    const float* __restrict__ ed, const float* __restrict__ vt,
    float* __restrict__ part) {
  int ch = blockIdx.x, j = blockIdx.y;
  int t = threadIdx.x;
  float acc[63];
  #pragma unroll
  for (int s=0;s<63;s++) acc[s]=0.f;
  int n0 = ch*JCHUNK, nend = min(n0+JCHUNK, NV);
  for (int n = n0 + t; n < nend; n += 256){
    float w = jreg[(size_t)j*NV + n];
    const float* sp = sd + (size_t)n*30;
    const float* ep = ed + (size_t)n*30;
    const float* vp = vt + (size_t)n*3;
    #pragma unroll
    for (int c=0;c<3;c++){
      #pragma unroll
      for (int q=0;q<10;q++){
        acc[c*21+q]    += w*sp[c*10+q];
        acc[c*21+10+q] += w*ep[c*10+q];
      }
      acc[c*21+20] += w*vp[c];
    }
  }
  #pragma unroll
  for (int s=0;s<63;s++){
    float a = acc[s];
    #pragma unroll
    for (int d=32; d>=1; d>>=1) a += __shfl_xor(a,d);
    acc[s]=a;
  }
  __shared__ float red[4][63];
  int w = t>>6, l = t&63;
  if (l==0){
    #pragma unroll
    for (int s=0;s<63;s++) red[w][s]=acc[s];
  }
  __syncthreads();
  if (t < 63){
    float a = red[0][t]+red[1][t]+red[2][t]+red[3][t];
    part[((size_t)j*JCH+ch)*63 + t] = a;
  }
}

// ---------------- joints[b][j][c] from JS partials + betas ------------------
__global__ __launch_bounds__(192) void k_joints2(
    const float* __restrict__ part, const float* __restrict__ bs,
    const float* __restrict__ es, float* __restrict__ joints) {
  int b = blockIdx.x, t = threadIdx.x;
  if (t >= NJ*3) return;
  int j = t/3, c = t - j*3;
  float S[21];
  #pragma unroll
  for (int q=0;q<21;q++) S[q]=0.f;
  for (int ch=0; ch<JCH; ch++){
    const float* p = part + ((size_t)j*JCH+ch)*63 + c*21;
    #pragma unroll
    for (int q=0;q<21;q++) S[q] += p[q];
  }
  float a = S[20];
  #pragma unroll
  for (int q=0;q<10;q++) a += S[q]*bs[b*10+q] + S[10+q]*es[b*10+q];
  joints[(size_t)b*NJ*3 + t] = a;
}

// ------- kinematic chain via wave-level tree scan (lane j = joint j) --------
// One wave per batch; chain matrices live in registers; parents via __shfl.
__global__ __launch_bounds__(256) void k_chain(
    const float* __restrict__ wrot, const float* __restrict__ bpose,
    const float* __restrict__ jaw, const float* __restrict__ leye,
    const float* __restrict__ reye, const float* __restrict__ lhand,
    const float* __restrict__ rhand, const float* __restrict__ wtsl,
    const float* __restrict__ joints,
    unsigned short* __restrict__ arelb, float* __restrict__ jout) {
  const int w = threadIdx.x >> 6, lane = threadIdx.x & 63;
  const int b = blockIdx.x*4 + w;
  const int j = lane;
  const bool act = (j < NJ);

  // local rotation
  float R[9] = {1.f,0.f,0.f, 0.f,1.f,0.f, 0.f,0.f,1.f};
  if (act){
    const float* rs = pose_src(j, b, wrot, bpose, jaw, leye, reye, lhand, rhand);
    #pragma unroll
    for (int i=0;i<9;i++) R[i]=rs[i];
  }
  // joint position (lane-resident), parent via shuffle
  float jx=0.f, jy=0.f, jz=0.f;
  if (act){
    const float* jb = joints + (size_t)b*NJ*3 + j*3;
    jx=jb[0]; jy=jb[1]; jz=jb[2];
  }
  int par = act ? c_parents[j] : 0;
  if (par < 0) par = 0;
  float px = __shfl(jx, par), py = __shfl(jy, par), pz = __shfl(jz, par);
  float t0, t1, t2;
  if (j == 0){ t0=jx; t1=jy; t2=jz; }
  else       { t0=jx-px; t1=jy-py; t2=jz-pz; }

  // M starts as local [R|t]; becomes global at round == depth
  float M[12];
  #pragma unroll
  for (int r=0;r<3;r++){
    M[r*4+0]=R[r*3+0]; M[r*4+1]=R[r*3+1]; M[r*4+2]=R[r*3+2]; M[r*4+3]= (r==0?t0:(r==1?t1:t2));
  }
  int dep = act ? c_depth[j] : 99;

  #pragma unroll
  for (int L=1; L<=10; L++){
    float pm[12];
    #pragma unroll
    for (int i=0;i<12;i++) pm[i] = __shfl(M[i], par);   // exec-uniform
    if (dep == L){
      #pragma unroll
      for (int r=0;r<3;r++){
        float p0=pm[r*4+0], p1=pm[r*4+1], p2=pm[r*4+2], p3=pm[r*4+3];
        M[r*4+0] = p0*R[0]+p1*R[3]+p2*R[6];
        M[r*4+1] = p0*R[1]+p1*R[4]+p2*R[7];
        M[r*4+2] = p0*R[2]+p1*R[5]+p2*R[8];
        M[r*4+3] = p0*t0 + p1*t1 + p2*t2 + p3;
      }
    }
  }

  float wx=wtsl[b*3+0], wy=wtsl[b*3+1], wz=wtsl[b*3+2];
  if (act){
    jout[((size_t)b*NJ+j)*3+0] = M[3]  + wx;
    jout[((size_t)b*NJ+j)*3+1] = M[7]  + wy;
    jout[((size_t)b*NJ+j)*3+2] = M[11] + wz;
  }
  // A_rel with t-correction; bf16 hi/lo split; pads (lanes>=55, e>=12) zeroed
  float A[12];
  #pragma unroll
  for (int r=0;r<3;r++){
    A[r*4+0]=M[r*4+0]; A[r*4+1]=M[r*4+1]; A[r*4+2]=M[r*4+2];
    A[r*4+3]=M[r*4+3] - (M[r*4+0]*jx + M[r*4+1]*jy + M[r*4+2]*jz);
  }
  unsigned short* ah = arelb + (size_t)(b*2+0)*16*64;
  unsigned short* al = arelb + (size_t)(b*2+1)*16*64;
  #pragma unroll
  for (int e=0;e<16;e++){
    float v = (e < 12 && act) ? A[e] : 0.f;
    unsigned short hi = f2bf(v);
    float lo = v - bf2f(hi);
    ah[e*64 + j] = hi;                 // contiguous across lanes per e
    al[e*64 + j] = f2bf(lo);
  }
}

// -------- v_posed = [pf|bs|es] @ [posedirs; sdT; edT] + vt  (bf16 MFMA) -----
// Barrier-free: B-fragments loaded DIRECTLY from global (8 strided dwords
// per frag = the exact MFMA B layout: lane(m16,quad) holds B[k=quad*8+j][col]).
// One block = 4 waves covers ALL 256 batches x 64 cols -> pd read once.
__global__ __launch_bounds__(256, 2) void k_vposed(
    const float* __restrict__ pd, const float* __restrict__ sdedT,
    const float* __restrict__ vt, const unsigned short* __restrict__ pfb,
    float* __restrict__ vsh) {
  const int tid  = threadIdx.x;
  const int w    = tid >> 6, lane = tid & 63;
  const int m16  = lane & 15, quad = lane >> 4;
  const int col0 = blockIdx.x * BN;

  f32x4 acc[4][4];
  #pragma unroll
  for (int i=0;i<4;i++)
    #pragma unroll
    for (int j=0;j<4;j++) acc[i][j] = (f32x4){0.f,0.f,0.f,0.f};

  // clamped B columns (cols >= VC read col VC-1; their acc is never stored)
  int bcol[4];
  #pragma unroll
  for (int ni=0;ni<4;ni++) bcol[ni] = min(col0 + ni*16 + m16, VC-1);

  const unsigned short* pfa = pfb + (size_t)(w*64 + m16)*KP + quad*8;

  // chunks 0..14: pure posedirs rows (k0+quad*8+7 <= 479 < 486)
  #pragma unroll 2
  for (int c=0; c<15; c++){
    const int k0 = c*BKC;
    bf16x8 a[4];
    #pragma unroll
    for (int mi=0;mi<4;mi++)
      a[mi] = *((const bf16x8*)(pfa + (size_t)mi*16*KP + k0));
    union { bf16x8 v; unsigned short s[8]; } bb[4];
    #pragma unroll
    for (int ni=0;ni<4;ni++){
      #pragma unroll
      for (int j=0;j<8;j++){
        int kk = k0 + quad*8 + j;
        bb[ni].s[j] = f2bf(pd[(size_t)kk*VC + bcol[ni]]);
      }
    }
    #pragma unroll
    for (int mi=0;mi<4;mi++)
      #pragma unroll
      for (int ni=0;ni<4;ni++)
        acc[mi][ni] = __builtin_amdgcn_mfma_f32_16x16x32_bf16(
                          a[mi], bb[ni].v, acc[mi][ni], 0, 0, 0);
  }
  // chunk 15: rows 480..485 pd, 486..505 sdedT, 506..511 zero
  {
    const int k0 = 15*BKC;
    bf16x8 a[4];
    #pragma unroll
    for (int mi=0;mi<4;mi++)
      a[mi] = *((const bf16x8*)(pfa + (size_t)mi*16*KP + k0));
    union { bf16x8 v; unsigned short s[8]; } bb[4];
    #pragma unroll
    for (int ni=0;ni<4;ni++){
      #pragma unroll
      for (int j=0;j<8;j++){
        int kk = k0 + quad*8 + j;
        float f = 0.f;
        if (kk < PB)      f = pd[(size_t)kk*VC + bcol[ni]];
        else if (kk < KS) f = sdedT[(size_t)(kk-PB)*VC + bcol[ni]];
        bb[ni].s[j] = f2bf(f);
      }
    }
    #pragma unroll
    for (int mi=0;mi<4;mi++)
      #pragma unroll
      for (int ni=0;ni<4;ni++)
        acc[mi][ni] = __builtin_amdgcn_mfma_f32_16x16x32_bf16(
                          a[mi], bb[ni].v, acc[mi][ni], 0, 0, 0);
  }
  // epilogue: vsh[row][col] = acc + v_template[col]
  #pragma unroll
  for (int mi=0;mi<4;mi++){
    int rbase = w*64 + mi*16 + quad*4;
    #pragma unroll
    for (int ni=0;ni<4;ni++){
      int col = col0 + ni*16 + m16;
      if (col < VC){
        float vtc = vt[col];
        #pragma unroll
        for (int r=0;r<4;r++)
          vsh[(size_t)(rbase + r)*VC + col] = acc[mi][ni][r] + vtc;
      }
    }
  }
}

// -------- skinning via MFMA: T(64v x 16e) = lw(64v x 64j) @ arelT(64j x 16e)
// block: 64 verts x 16 batches; hi/lo split on both operands (3 MFMAs).
__global__ __launch_bounds__(256) void k_verts(
    const unsigned short* __restrict__ lwb, const unsigned short* __restrict__ arelb,
    const float* __restrict__ wtsl, float* __restrict__ out) {
  __shared__ float sT[16*64*17];           // 69632 B, stride 17 (coprime 32)
  const int tid = threadIdx.x, w = tid >> 6, lane = tid & 63;
  const int m16 = lane & 15, quad = lane >> 4;
  const int n0 = blockIdx.x*64;
  const int b0 = blockIdx.y*16;

  // A fragments (lw): 4 vert-tiles x 2 k-chunks x {hi,lo}
  bf16x8 ahh[4][2], all[4][2];
  #pragma unroll
  for (int t4=0;t4<4;t4++){
    int row = n0 + t4*16 + m16;
    #pragma unroll
    for (int kc=0;kc<2;kc++){
      ahh[t4][kc] = *((const bf16x8*)(lwb + (size_t)row*64 + kc*32 + quad*8));
      all[t4][kc] = *((const bf16x8*)(lwb + (size_t)NVP*64 + (size_t)row*64 + kc*32 + quad*8));
    }
  }
  for (int bi=0; bi<4; bi++){
    int b = b0 + w*4 + bi;
    bf16x8 bh[2], bl[2];
    #pragma unroll
    for (int kc=0;kc<2;kc++){
      bh[kc] = *((const bf16x8*)(arelb + ((size_t)(b*2+0)*16 + m16)*64 + kc*32 + quad*8));
      bl[kc] = *((const bf16x8*)(arelb + ((size_t)(b*2+1)*16 + m16)*64 + kc*32 + quad*8));
    }
    f32x4 acc[4];
    #pragma unroll
    for (int t4=0;t4<4;t4++) acc[t4] = (f32x4){0.f,0.f,0.f,0.f};
    #pragma unroll
    for (int t4=0;t4<4;t4++)
      #pragma unroll
      for (int kc=0;kc<2;kc++){
        acc[t4] = __builtin_amdgcn_mfma_f32_16x16x32_bf16(ahh[t4][kc], bh[kc], acc[t4], 0,0,0);
        acc[t4] = __builtin_amdgcn_mfma_f32_16x16x32_bf16(all[t4][kc], bh[kc], acc[t4], 0,0,0);
        acc[t4] = __builtin_amdgcn_mfma_f32_16x16x32_bf16(ahh[t4][kc], bl[kc], acc[t4], 0,0,0);
      }
    if (m16 < 12){
      int slot = w*4 + bi;
      #pragma unroll
      for (int t4=0;t4<4;t4++){
        #pragma unroll
        for (int r=0;r<4;r++){
          int vert = t4*16 + quad*4 + r;
          sT[(slot*64 + vert)*17 + m16] = acc[t4][r];
        }
      }
    }
  }
  __syncthreads();
  // apply T to v_posed (in place on out's verts region)
  #pragma unroll
  for (int it=0; it<4; it++){
    int pid = it*256 + tid;
    int bb = pid >> 6, v = pid & 63;
    int n = n0 + v;
    if (n >= NV) continue;
    int b = b0 + bb;
    const float* Tp = &sT[(bb*64 + v)*17];
    float T[12];
    #pragma unroll
    for (int e=0;e<12;e++) T[e] = Tp[e];
    float* op = out + ((size_t)b*NV + n)*3;
    float x=op[0], y=op[1], z=op[2];
    float tx=wtsl[b*3+0], ty=wtsl[b*3+1], tz=wtsl[b*3+2];
    op[0] = T[0]*x + T[1]*y + T[2] *z + T[3]  + tx;
    op[1] = T[4]*x + T[5]*y + T[6] *z + T[7]  + ty;
    op[2] = T[8]*x + T[9]*y + T[10]*z + T[11] + tz;
  }
}

extern "C" void kernel_launch(void* const* d_in, const int* in_sizes, int n_in,
                              void* d_out, int out_size, void* d_ws, size_t ws_size,
                              hipStream_t stream) {
  const float* wrot   = (const float*)d_in[0];
  const float* wtsl   = (const float*)d_in[1];
  const float* bshape = (const float*)d_in[2];
  const float* bpose  = (const float*)d_in[3];
  const float* lhand  = (const float*)d_in[4];
  const float* rhand  = (const float*)d_in[5];
  const float* eshape = (const float*)d_in[6];
  const float* jaw    = (const float*)d_in[7];
  const float* leye   = (const float*)d_in[8];
  const float* reye   = (const float*)d_in[9];
  const float* vt     = (const float*)d_in[10];
  const float* sd     = (const float*)d_in[11];
  const float* ed     = (const float*)d_in[12];
  const float* pd     = (const float*)d_in[13];
  const float* jreg   = (const float*)d_in[14];
  const float* lw     = (const float*)d_in[15];
  float* out = (float*)d_out;

  float* vsh  = out;                               // verts region = v_posed scratch
  float* jout = out + (size_t)BATCH*NV*3;

  float* ws     = (float*)d_ws;                    // ~7 MB total
  float* joints = ws;                                      // 256*165   = 42240
  float* part   = joints + (size_t)BATCH*NJ*3;             // 55*8*63   = 27720
  float* sdedT  = part   + (size_t)NJ*JCH*63;              // 20*VC     = 628500
  unsigned short* pfb   = (unsigned short*)(sdedT + (size_t)20*VC);   // 256*512
  unsigned short* lwb   = pfb + (size_t)BATCH*KP;                     // 2*NVP*64
  unsigned short* arelb = lwb + (size_t)2*NVP*64;                     // 256*2*16*64

  const int PREP_BLOCKS = (NVP*64)/256 + (20*VC + 255)/256;   // 2624 + 2456

  k_prep    <<<PREP_BLOCKS, 256, 0, stream>>>(lw, sd, ed, lwb, sdedT);
  k_posefeat<<<BATCH, 512, 0, stream>>>(bpose, jaw, leye, reye, lhand, rhand,
                                        bshape, eshape, pfb);
  k_jsmall  <<<dim3(JCH, NJ), 256, 0, stream>>>(jreg, sd, ed, vt, part);
  k_joints2 <<<BATCH, 192, 0, stream>>>(part, bshape, eshape, joints);
  k_chain   <<<64, 256, 0, stream>>>(wrot, bpose, jaw, leye, reye, lhand, rhand,
                                     wtsl, joints, arelb, jout);
  k_vposed  <<<(VC+BN-1)/BN, 256, 0, stream>>>(pd, sdedT, vt, pfb, vsh);
  k_verts   <<<dim3(NVP/64, 16), 256, 0, stream>>>(lwb, arelb, wtsl, out);
}